// Round 2
// baseline (555.678 us; speedup 1.0000x reference)
//
#include <hip/hip_runtime.h>

#define M_DIM 4096
#define K_DIM 4096
#define N_DIM 11008
#define BM 256
#define BN 256
#define BK 128   // bytes of K per tile iteration (int8)
#define NTILES (K_DIM / BK)   // 32

typedef int v4i  __attribute__((ext_vector_type(4)));
typedef int v16i __attribute__((ext_vector_type(16)));

// s_waitcnt immediates (gfx90a+ encoding: vmcnt[3:0]+[15:14], exp[6:4], lgkm[13:8])
#define WAIT_VM8 0x3F78   // vmcnt<=8
#define WAIT_VM0 0x3F70   // vmcnt<=0

__device__ __forceinline__ void load_lds16(const void* g, void* l) {
    __builtin_amdgcn_global_load_lds(
        (const __attribute__((address_space(1))) void*)g,
        (__attribute__((address_space(3))) void*)l,
        16, 0, 0);
}

__device__ __forceinline__ unsigned int pack4(int4 v, int zp) {
    return ((unsigned int)(v.x - zp) & 0xFF)
         | (((unsigned int)(v.y - zp) & 0xFF) << 8)
         | (((unsigned int)(v.z - zp) & 0xFF) << 16)
         | (((unsigned int)(v.w - zp) & 0xFF) << 24);
}

// 16 output bytes per thread: 4x int4 loads -> one uint4 store (16B/lane both ways)
__global__ void pack_x_kernel(const int* __restrict__ x, unsigned int* __restrict__ out,
                              const int* __restrict__ zp_p, int n16) {
    int i = blockIdx.x * blockDim.x + threadIdx.x;
    if (i >= n16) return;
    const int zp = zp_p[0];
    const int4* p = (const int4*)x + i * 4;
    uint4 o;
    o.x = pack4(p[0], zp);
    o.y = pack4(p[1], zp);
    o.z = pack4(p[2], zp);
    o.w = pack4(p[3], zp);
    ((uint4*)out)[i] = o;
}

__global__ void pack_w_kernel(const int* __restrict__ w, unsigned int* __restrict__ out, int n16) {
    int i = blockIdx.x * blockDim.x + threadIdx.x;
    if (i >= n16) return;
    const int4* p = (const int4*)w + i * 4;
    uint4 o;
    o.x = pack4(p[0], 0);
    o.y = pack4(p[1], 0);
    o.z = pack4(p[2], 0);
    o.w = pack4(p[3], 0);
    ((uint4*)out)[i] = o;
}

// LDS tile layout (per buffer): row-major, 8 granules of 16B per 128B row;
// granule g of row r stored at slot r*8 + (g ^ (r&7)). LDS dest of
// global_load_lds stays LINEAR (HW writes base+lane*16); the swizzle is
// applied on the per-lane GLOBAL source address instead.
__global__ __launch_bounds__(512, 2) void gemm_i8_kernel(
    const signed char* __restrict__ A8,   // [M][K] int8 (x - zp)
    const signed char* __restrict__ B8,   // [N][K] int8 (w)
    const float* __restrict__ bias,
    const float* __restrict__ xs_p, const float* __restrict__ ws_p,
    const float* __restrict__ os_p, const int* __restrict__ ozp_p,
    int* __restrict__ out) {
    __shared__ v4i As0[BM * BK / 16];   // 32 KB each
    __shared__ v4i Bs0[BN * BK / 16];
    __shared__ v4i As1[BM * BK / 16];
    __shared__ v4i Bs1[BN * BK / 16];

    const int tid  = threadIdx.x;
    const int lane = tid & 63;
    const int wave = tid >> 6;

    // ---- XCD-aware block swizzle: 688 blocks = 8 XCD x (2 m-tiles x 43 n-tiles)
    // Concurrent blocks on an XCD share one A panel (L2-resident).
    const int bid   = blockIdx.x;
    const int xcd   = bid & 7;
    const int local = bid >> 3;                    // [0, 86)
    const int m_blk = xcd * 2 + (local >= 43 ? 1 : 0);
    const int n_blk = (local >= 43) ? (local - 43) : local;
    const int m0 = m_blk * BM;
    const int n0 = n_blk * BN;

    // ---- staging addresses: 8 granules per thread (4 A + 4 B) per tile ----
    long offA[4], offB[4];
    int  ldsOff[4];
#pragma unroll
    for (int j = 0; j < 4; ++j) {
        const int s   = tid + 512 * j;
        const int row = s >> 3;
        const int gg  = (s & 7) ^ (row & 7);
        offA[j]   = (long)(m0 + row) * K_DIM + gg * 16;
        offB[j]   = (long)(n0 + row) * K_DIM + gg * 16;
        ldsOff[j] = s;   // v4i slot (linear — matches global_load_lds lane order)
    }

    // ---- fragment slots for mfma_i32_32x32x32_i8 ----
    // A/B operand: m(or n) = lane&31, k bytes [(lane>>5)*16, +16)
    // 8 waves, 2M x 4N: per-wave output 128x64 -> 6 ds_reads per 8 MFMA (0.75x)
    const int waveM = wave >> 2, waveN = wave & 3;
    const int l31 = lane & 31, h = lane >> 5;
    int aSlot[4][4], bSlot[2][4];
#pragma unroll
    for (int mt = 0; mt < 4; ++mt) {
        const int rA = waveM * 128 + mt * 32 + l31;
#pragma unroll
        for (int s = 0; s < 4; ++s) {
            const int g = 2 * s + h;
            aSlot[mt][s] = rA * 8 + (g ^ (rA & 7));
        }
    }
#pragma unroll
    for (int nt = 0; nt < 2; ++nt) {
        const int rB = waveN * 64 + nt * 32 + l31;
#pragma unroll
        for (int s = 0; s < 4; ++s) {
            const int g = 2 * s + h;
            bSlot[nt][s] = rB * 8 + (g ^ (rB & 7));
        }
    }

    v16i acc[4][2];
#pragma unroll
    for (int mt = 0; mt < 4; ++mt)
#pragma unroll
        for (int nt = 0; nt < 2; ++nt)
#pragma unroll
            for (int r = 0; r < 16; ++r) acc[mt][nt][r] = 0;

    // ---- helpers ----
    auto stage = [&](int tile, v4i* Asb, v4i* Bsb) {
        const long koff = (long)tile * BK;
#pragma unroll
        for (int j = 0; j < 4; ++j) load_lds16(A8 + offA[j] + koff, (char*)(Asb + ldsOff[j]));
#pragma unroll
        for (int j = 0; j < 4; ++j) load_lds16(B8 + offB[j] + koff, (char*)(Bsb + ldsOff[j]));
    };

    // 4 sub-phases per K-tile (one 32B k-step each), barrier-sandwiched
    // setprio'd MFMA clusters (T3+T5 pattern): ds_read bursts of phase s
    // overlap matrix-pipe execution of phase s-1's MFMAs.
    auto compute = [&](const v4i* Asb, const v4i* Bsb) {
#pragma unroll
        for (int s = 0; s < 4; ++s) {
            v4i a[4], b[2];
#pragma unroll
            for (int mt = 0; mt < 4; ++mt) a[mt] = Asb[aSlot[mt][s]];
#pragma unroll
            for (int nt = 0; nt < 2; ++nt) b[nt] = Bsb[bSlot[nt][s]];
            __builtin_amdgcn_s_barrier();           // raw barrier: no vmcnt drain
            __builtin_amdgcn_s_setprio(1);
#pragma unroll
            for (int mt = 0; mt < 4; ++mt)
#pragma unroll
                for (int nt = 0; nt < 2; ++nt)
                    acc[mt][nt] = __builtin_amdgcn_mfma_i32_32x32x32_i8(
                        a[mt], b[nt], acc[mt][nt], 0, 0, 0);
            __builtin_amdgcn_s_setprio(0);
            __builtin_amdgcn_s_barrier();
        }
    };

    // ---- async double-buffered pipeline, counted vmcnt (never drains to 0
    // in the main loop: next tile's 8 loads stay in flight across barriers) ----
    stage(0, As0, Bs0);          // 8 vm-ops in flight
    stage(1, As1, Bs1);          // 16 in flight

#pragma unroll 1
    for (int kk = 0; kk < 15; ++kk) {
        const int k = 2 * kk;
        // even: consume buf0
        __builtin_amdgcn_s_waitcnt(WAIT_VM8);   // tile k landed; tile k+1 still flying
        __builtin_amdgcn_s_barrier();
        compute(As0, Bs0);                      // ends with barrier: buf0 fully read
        stage(k + 2, As0, Bs0);
        // odd: consume buf1
        __builtin_amdgcn_s_waitcnt(WAIT_VM8);   // tile k+1 landed; tile k+2 flying
        __builtin_amdgcn_s_barrier();
        compute(As1, Bs1);
        stage(k + 3, As1, Bs1);
    }
    // peeled tail: tiles 30, 31
    __builtin_amdgcn_s_waitcnt(WAIT_VM8);
    __builtin_amdgcn_s_barrier();
    compute(As0, Bs0);
    __builtin_amdgcn_s_waitcnt(WAIT_VM0);
    __builtin_amdgcn_s_barrier();
    compute(As1, Bs1);

    // ---- epilogue: dequant + bias, requant to [0,255] ----
    // C/D 32x32: col = lane&31, row = (reg&3) + 8*(reg>>2) + 4*(lane>>5)
    const float scale  = xs_p[0] * ws_p[0];
    const float inv_os = 1.0f / os_p[0];
    const int   ozp    = ozp_p[0];
#pragma unroll
    for (int mt = 0; mt < 4; ++mt) {
        const int rbase = m0 + waveM * 128 + mt * 32 + 4 * h;
#pragma unroll
        for (int nt = 0; nt < 2; ++nt) {
            const int col = n0 + waveN * 64 + nt * 32 + l31;
            const float bv = bias[col];
#pragma unroll
            for (int r = 0; r < 16; ++r) {
                const int row = rbase + (r & 3) + 8 * (r >> 2);
                float y = (float)acc[mt][nt][r] * scale + bv;
                int q = (int)rintf(y * inv_os) + ozp;
                q = q < 0 ? 0 : (q > 255 ? 255 : q);
                out[(long)row * N_DIM + col] = q;
            }
        }
    }
}

extern "C" void kernel_launch(void* const* d_in, const int* in_sizes, int n_in,
                              void* d_out, int out_size, void* d_ws, size_t ws_size,
                              hipStream_t stream) {
    const int*   x_q  = (const int*)d_in[0];
    const int*   w_q  = (const int*)d_in[1];
    const float* bias = (const float*)d_in[2];
    const float* xs   = (const float*)d_in[3];
    const float* wsc  = (const float*)d_in[4];
    const float* os   = (const float*)d_in[5];
    const int*   xzp  = (const int*)d_in[6];
    const int*   ozp  = (const int*)d_in[7];

    signed char* x8 = (signed char*)d_ws;                               // 16 MB
    signed char* w8 = (signed char*)d_ws + (size_t)M_DIM * K_DIM;       // 45 MB

    const int nx16 = M_DIM * K_DIM / 16;
    pack_x_kernel<<<(nx16 + 255) / 256, 256, 0, stream>>>(x_q, (unsigned int*)x8, xzp, nx16);
    const int nw16 = N_DIM * K_DIM / 16;
    pack_w_kernel<<<(nw16 + 255) / 256, 256, 0, stream>>>(w_q, (unsigned int*)w8, nw16);

    const int nblocks = (M_DIM / BM) * (N_DIM / BN);   // 16 * 43 = 688
    gemm_i8_kernel<<<nblocks, 512, 0, stream>>>(x8, w8, bias, xs, wsc, os, ozp, (int*)d_out);
}

// Round 3
// 550.042 us; speedup vs baseline: 1.0102x; 1.0102x over previous
//
#include <hip/hip_runtime.h>

#define M_DIM 4096
#define K_DIM 4096
#define N_DIM 11008
#define BM 256
#define BN 256
#define BK 128   // bytes of K per tile iteration (int8)
#define NTILES (K_DIM / BK)   // 32

typedef int v4i  __attribute__((ext_vector_type(4)));
typedef int v16i __attribute__((ext_vector_type(16)));

// s_waitcnt immediates (gfx90a+ encoding: vmcnt[3:0]+[15:14], exp[6:4], lgkm[13:8])
#define WAIT_VM8 0x3F78   // vmcnt<=8
#define WAIT_VM0 0x3F70   // vmcnt<=0

__device__ __forceinline__ void load_lds16(const void* g, void* l) {
    __builtin_amdgcn_global_load_lds(
        (const __attribute__((address_space(1))) void*)g,
        (__attribute__((address_space(3))) void*)l,
        16, 0, 0);
}

__device__ __forceinline__ unsigned int pack4(int4 v, int zp) {
    return ((unsigned int)(v.x - zp) & 0xFF)
         | (((unsigned int)(v.y - zp) & 0xFF) << 8)
         | (((unsigned int)(v.z - zp) & 0xFF) << 16)
         | (((unsigned int)(v.w - zp) & 0xFF) << 24);
}

// Fused pack: one launch covers x (with zero-point) then w (zp=0).
// 16 output bytes per thread: 4x int4 loads -> one uint4 store.
__global__ void pack_both_kernel(const int* __restrict__ x, const int* __restrict__ w,
                                 unsigned int* __restrict__ x8, unsigned int* __restrict__ w8,
                                 const int* __restrict__ zp_p, int nx16, int nw16) {
    int i = blockIdx.x * blockDim.x + threadIdx.x;
    if (i < nx16) {
        const int zp = zp_p[0];
        const int4* p = (const int4*)x + i * 4;
        uint4 o;
        o.x = pack4(p[0], zp);
        o.y = pack4(p[1], zp);
        o.z = pack4(p[2], zp);
        o.w = pack4(p[3], zp);
        ((uint4*)x8)[i] = o;
    } else {
        int j = i - nx16;
        if (j >= nw16) return;
        const int4* p = (const int4*)w + j * 4;
        uint4 o;
        o.x = pack4(p[0], 0);
        o.y = pack4(p[1], 0);
        o.z = pack4(p[2], 0);
        o.w = pack4(p[3], 0);
        ((uint4*)w8)[j] = o;
    }
}

// LDS tile layout (per buffer): row-major, 8 granules of 16B per 128B row;
// granule g of row r stored at slot r*8 + (g ^ (r&7)). LDS dest of
// global_load_lds stays LINEAR (HW writes base+lane*16); the swizzle is
// applied on the per-lane GLOBAL source address instead.
//
// Schedule: R0-proven 2-barriers-per-tile (no inner phase barriers).
// 8 waves (2M x 4N, per-wave 128x64): 6 ds_reads per 8 MFMA = 0.75x the
// LDS traffic of the 128^2 kernel; per tile MFMA (2340 cyc/SIMD) now
// exceeds LDS (1150 cyc/CU) -> MFMA-bound balance.
__global__ __launch_bounds__(512, 2) void gemm_i8_kernel(
    const signed char* __restrict__ A8,   // [M][K] int8 (x - zp)
    const signed char* __restrict__ B8,   // [N][K] int8 (w)
    const float* __restrict__ bias,
    const float* __restrict__ xs_p, const float* __restrict__ ws_p,
    const float* __restrict__ os_p, const int* __restrict__ ozp_p,
    int* __restrict__ out) {
    __shared__ v4i As0[BM * BK / 16];   // 32 KB each
    __shared__ v4i Bs0[BN * BK / 16];
    __shared__ v4i As1[BM * BK / 16];
    __shared__ v4i Bs1[BN * BK / 16];

    const int tid  = threadIdx.x;
    const int lane = tid & 63;
    const int wave = tid >> 6;

    // ---- XCD-aware block swizzle: 688 blocks = 8 XCD x (2 m-tiles x 43 n-tiles)
    const int bid   = blockIdx.x;
    const int xcd   = bid & 7;
    const int local = bid >> 3;                    // [0, 86)
    const int m_blk = xcd * 2 + (local >= 43 ? 1 : 0);
    const int n_blk = (local >= 43) ? (local - 43) : local;
    const int m0 = m_blk * BM;
    const int n0 = n_blk * BN;

    // ---- staging addresses: 8 granules per thread (4 A + 4 B) per tile ----
    long offA[4], offB[4];
    int  ldsOff[4];
#pragma unroll
    for (int j = 0; j < 4; ++j) {
        const int s   = tid + 512 * j;
        const int row = s >> 3;
        const int gg  = (s & 7) ^ (row & 7);
        offA[j]   = (long)(m0 + row) * K_DIM + gg * 16;
        offB[j]   = (long)(n0 + row) * K_DIM + gg * 16;
        ldsOff[j] = s;   // v4i slot (linear — matches global_load_lds lane order)
    }

    // ---- fragment slots for mfma_i32_32x32x32_i8 ----
    // A/B operand: m(or n) = lane&31, k bytes [(lane>>5)*16, +16)
    const int waveM = wave >> 2, waveN = wave & 3;
    const int l31 = lane & 31, h = lane >> 5;
    int aSlot[4][4], bSlot[2][4];
#pragma unroll
    for (int mt = 0; mt < 4; ++mt) {
        const int rA = waveM * 128 + mt * 32 + l31;
#pragma unroll
        for (int s = 0; s < 4; ++s) {
            const int g = 2 * s + h;
            aSlot[mt][s] = rA * 8 + (g ^ (rA & 7));
        }
    }
#pragma unroll
    for (int nt = 0; nt < 2; ++nt) {
        const int rB = waveN * 64 + nt * 32 + l31;
#pragma unroll
        for (int s = 0; s < 4; ++s) {
            const int g = 2 * s + h;
            bSlot[nt][s] = rB * 8 + (g ^ (rB & 7));
        }
    }

    v16i acc[4][2];
#pragma unroll
    for (int mt = 0; mt < 4; ++mt)
#pragma unroll
        for (int nt = 0; nt < 2; ++nt)
#pragma unroll
            for (int r = 0; r < 16; ++r) acc[mt][nt][r] = 0;

    // ---- helpers ----
    auto stage = [&](int tile, v4i* Asb, v4i* Bsb) {
        const long koff = (long)tile * BK;
#pragma unroll
        for (int j = 0; j < 4; ++j) load_lds16(A8 + offA[j] + koff, (char*)(Asb + ldsOff[j]));
#pragma unroll
        for (int j = 0; j < 4; ++j) load_lds16(B8 + offB[j] + koff, (char*)(Bsb + ldsOff[j]));
    };
    // No inner barriers: let 2-waves/SIMD drift provide ds_read/MFMA overlap
    // (the proven R0 schedule; inner barriers measured -28% in R2).
    auto compute = [&](const v4i* Asb, const v4i* Bsb) {
#pragma unroll
        for (int s = 0; s < 4; ++s) {
            v4i a[4], b[2];
#pragma unroll
            for (int mt = 0; mt < 4; ++mt) a[mt] = Asb[aSlot[mt][s]];
#pragma unroll
            for (int nt = 0; nt < 2; ++nt) b[nt] = Bsb[bSlot[nt][s]];
#pragma unroll
            for (int mt = 0; mt < 4; ++mt)
#pragma unroll
                for (int nt = 0; nt < 2; ++nt)
                    acc[mt][nt] = __builtin_amdgcn_mfma_i32_32x32x32_i8(
                        a[mt], b[nt], acc[mt][nt], 0, 0, 0);
        }
    };

    // ---- async double-buffered pipeline, counted vmcnt (never drains to 0
    // in the main loop) ----
    stage(0, As0, Bs0);          // 8 vm-ops in flight
    stage(1, As1, Bs1);          // 16 in flight

#pragma unroll 1
    for (int kk = 0; kk < 15; ++kk) {
        const int k = 2 * kk;
        // even: consume buf0
        __builtin_amdgcn_s_waitcnt(WAIT_VM8);   // tile k landed; tile k+1 still flying
        __builtin_amdgcn_s_barrier();
        compute(As0, Bs0);
        __builtin_amdgcn_s_barrier();           // everyone done reading buf0
        stage(k + 2, As0, Bs0);
        // odd: consume buf1
        __builtin_amdgcn_s_waitcnt(WAIT_VM8);   // tile k+1 landed; tile k+2 flying
        __builtin_amdgcn_s_barrier();
        compute(As1, Bs1);
        __builtin_amdgcn_s_barrier();           // everyone done reading buf1
        stage(k + 3, As1, Bs1);
    }
    // peeled tail: tiles 30, 31
    __builtin_amdgcn_s_waitcnt(WAIT_VM8);
    __builtin_amdgcn_s_barrier();
    compute(As0, Bs0);
    __builtin_amdgcn_s_waitcnt(WAIT_VM0);
    __builtin_amdgcn_s_barrier();
    compute(As1, Bs1);

    // ---- epilogue: dequant + bias, requant to [0,255] ----
    // C/D 32x32: col = lane&31, row = (reg&3) + 8*(reg>>2) + 4*(lane>>5)
    const float scale  = xs_p[0] * ws_p[0];
    const float inv_os = 1.0f / os_p[0];
    const int   ozp    = ozp_p[0];
#pragma unroll
    for (int mt = 0; mt < 4; ++mt) {
        const int rbase = m0 + waveM * 128 + mt * 32 + 4 * h;
#pragma unroll
        for (int nt = 0; nt < 2; ++nt) {
            const int col = n0 + waveN * 64 + nt * 32 + l31;
            const float bv = bias[col];
#pragma unroll
            for (int r = 0; r < 16; ++r) {
                const int row = rbase + (r & 3) + 8 * (r >> 2);
                float y = (float)acc[mt][nt][r] * scale + bv;
                int q = (int)rintf(y * inv_os) + ozp;
                q = q < 0 ? 0 : (q > 255 ? 255 : q);
                out[(long)row * N_DIM + col] = q;
            }
        }
    }
}

extern "C" void kernel_launch(void* const* d_in, const int* in_sizes, int n_in,
                              void* d_out, int out_size, void* d_ws, size_t ws_size,
                              hipStream_t stream) {
    const int*   x_q  = (const int*)d_in[0];
    const int*   w_q  = (const int*)d_in[1];
    const float* bias = (const float*)d_in[2];
    const float* xs   = (const float*)d_in[3];
    const float* wsc  = (const float*)d_in[4];
    const float* os   = (const float*)d_in[5];
    const int*   xzp  = (const int*)d_in[6];
    const int*   ozp  = (const int*)d_in[7];

    signed char* x8 = (signed char*)d_ws;                               // 16 MB
    signed char* w8 = (signed char*)d_ws + (size_t)M_DIM * K_DIM;       // 45 MB

    const int nx16 = M_DIM * K_DIM / 16;
    const int nw16 = N_DIM * K_DIM / 16;
    const int npack = nx16 + nw16;
    pack_both_kernel<<<(npack + 255) / 256, 256, 0, stream>>>(
        x_q, w_q, (unsigned int*)x8, (unsigned int*)w8, xzp, nx16, nw16);

    const int nblocks = (M_DIM / BM) * (N_DIM / BN);   // 16 * 43 = 688
    gemm_i8_kernel<<<nblocks, 512, 0, stream>>>(x8, w8, bias, xs, wsc, os, ozp, (int*)d_out);
}

// Round 4
// 546.222 us; speedup vs baseline: 1.0173x; 1.0070x over previous
//
#include <hip/hip_runtime.h>

#define M_DIM 4096
#define K_DIM 4096
#define N_DIM 11008
#define BM 256
#define BN 128
#define BK 64    // bytes of K per tile iteration (int8)
#define NTILES (K_DIM / BK)   // 64

typedef int v4i  __attribute__((ext_vector_type(4)));
typedef int v16i __attribute__((ext_vector_type(16)));

// s_waitcnt immediates (gfx90a+ encoding: vmcnt[3:0]+[15:14], exp[6:4], lgkm[13:8])
#define WAIT_VM6 0x3F76   // vmcnt<=6  (one stage() = 6 loads still in flight)
#define WAIT_VM0 0x3F70   // vmcnt<=0

__device__ __forceinline__ void load_lds16(const void* g, void* l) {
    __builtin_amdgcn_global_load_lds(
        (const __attribute__((address_space(1))) void*)g,
        (__attribute__((address_space(3))) void*)l,
        16, 0, 0);
}

__device__ __forceinline__ unsigned int pack4(int4 v, int zp) {
    return ((unsigned int)(v.x - zp) & 0xFF)
         | (((unsigned int)(v.y - zp) & 0xFF) << 8)
         | (((unsigned int)(v.z - zp) & 0xFF) << 16)
         | (((unsigned int)(v.w - zp) & 0xFF) << 24);
}

// Fused pack: one launch covers x (with zero-point) then w (zp=0).
__global__ void pack_both_kernel(const int* __restrict__ x, const int* __restrict__ w,
                                 unsigned int* __restrict__ x8, unsigned int* __restrict__ w8,
                                 const int* __restrict__ zp_p, int nx16, int nw16) {
    int i = blockIdx.x * blockDim.x + threadIdx.x;
    if (i < nx16) {
        const int zp = zp_p[0];
        const int4* p = (const int4*)x + i * 4;
        uint4 o;
        o.x = pack4(p[0], zp);
        o.y = pack4(p[1], zp);
        o.z = pack4(p[2], zp);
        o.w = pack4(p[3], zp);
        ((uint4*)x8)[i] = o;
    } else {
        int j = i - nx16;
        if (j >= nw16) return;
        const int4* p = (const int4*)w + j * 4;
        uint4 o;
        o.x = pack4(p[0], 0);
        o.y = pack4(p[1], 0);
        o.z = pack4(p[2], 0);
        o.w = pack4(p[3], 0);
        ((uint4*)w8)[j] = o;
    }
}

// Config rationale (R3 post-mortem):
//  - 2 blocks/CU co-residency is the proven bubble-absorber (R0: 44% util;
//    R2/R3 single-block: 30-36% with ~3500 cyc/tile exposed sync bubbles).
//  - Register budget locks co-residency: acc[4][2]=128 AGPR + ~100 VGPR
//    <= 256/wave -> 2 waves/SIMD -> two 4-wave blocks/CU.
//  - Wave tile 128x64 keeps 0.75 ds_reads/MFMA; BK=64 drops stage traffic
//    to 0.375 KB/MFMA -> total LDS 1.125 KB/MFMA vs R0's 1.5 (LDS-pipe cap
//    rises from ~51% to ~70%+ util).
// LDS layout: 4 granules of 16B per 64B row; granule g of row r at slot
// r*4 + (g ^ (r&3)). LDS dest of global_load_lds stays LINEAR; the swizzle
// is applied on the per-lane GLOBAL source address.
__global__ __launch_bounds__(256, 2) void gemm_i8_kernel(
    const signed char* __restrict__ A8,   // [M][K] int8 (x - zp)
    const signed char* __restrict__ B8,   // [N][K] int8 (w)
    const float* __restrict__ bias,
    const float* __restrict__ xs_p, const float* __restrict__ ws_p,
    const float* __restrict__ os_p, const int* __restrict__ ozp_p,
    int* __restrict__ out) {
    __shared__ v4i As0[BM * BK / 16];   // 16 KB
    __shared__ v4i Bs0[BN * BK / 16];   // 8 KB
    __shared__ v4i As1[BM * BK / 16];
    __shared__ v4i Bs1[BN * BK / 16];   // 48 KB total -> 2 blocks/CU (96 of 160 KB)

    const int tid  = threadIdx.x;
    const int lane = tid & 63;
    const int wave = tid >> 6;

    // ---- XCD-aware block swizzle: 1376 blocks = 8 XCD x (2 m-tiles x 86 n-tiles)
    // Consecutive blocks on an XCD share the same 256-row A panel (L2-hit).
    const int bid   = blockIdx.x;
    const int xcd   = bid & 7;
    const int local = bid >> 3;                    // [0, 172)
    const int m_blk = xcd * 2 + (local >= 86 ? 1 : 0);
    const int n_blk = (local >= 86) ? (local - 86) : local;
    const int m0 = m_blk * BM;
    const int n0 = n_blk * BN;

    // ---- staging addresses: per thread 4 A granules + 2 B granules per tile ----
    long offA[4], offB[2];
    int  ldsA[4], ldsB[2];
#pragma unroll
    for (int j = 0; j < 4; ++j) {
        const int s   = tid + 256 * j;             // A slot [0,1024)
        const int row = s >> 2;
        const int gg  = (s & 3) ^ (row & 3);       // pre-swizzled source granule
        offA[j] = (long)(m0 + row) * K_DIM + gg * 16;
        ldsA[j] = s;
    }
#pragma unroll
    for (int j = 0; j < 2; ++j) {
        const int s   = tid + 256 * j;             // B slot [0,512)
        const int row = s >> 2;
        const int gg  = (s & 3) ^ (row & 3);
        offB[j] = (long)(n0 + row) * K_DIM + gg * 16;
        ldsB[j] = s;
    }

    // ---- fragment slots for mfma_i32_32x32x32_i8 ----
    // A/B operand: m(or n) = lane&31, k bytes [(lane>>5)*16, +16)
    const int waveM = wave >> 1, waveN = wave & 1;
    const int l31 = lane & 31, h = lane >> 5;
    int aSlot[4][2], bSlot[2][2];
#pragma unroll
    for (int mt = 0; mt < 4; ++mt) {
        const int rA = waveM * 128 + mt * 32 + l31;
#pragma unroll
        for (int s = 0; s < 2; ++s) {
            const int g = 2 * s + h;
            aSlot[mt][s] = rA * 4 + (g ^ (rA & 3));
        }
    }
#pragma unroll
    for (int nt = 0; nt < 2; ++nt) {
        const int rB = waveN * 64 + nt * 32 + l31;
#pragma unroll
        for (int s = 0; s < 2; ++s) {
            const int g = 2 * s + h;
            bSlot[nt][s] = rB * 4 + (g ^ (rB & 3));
        }
    }

    v16i acc[4][2];
#pragma unroll
    for (int mt = 0; mt < 4; ++mt)
#pragma unroll
        for (int nt = 0; nt < 2; ++nt)
#pragma unroll
            for (int r = 0; r < 16; ++r) acc[mt][nt][r] = 0;

    // ---- helpers ----
    auto stage = [&](int tile, v4i* Asb, v4i* Bsb) {
        const long koff = (long)tile * BK;
#pragma unroll
        for (int j = 0; j < 4; ++j) load_lds16(A8 + offA[j] + koff, (char*)(Asb + ldsA[j]));
#pragma unroll
        for (int j = 0; j < 2; ++j) load_lds16(B8 + offB[j] + koff, (char*)(Bsb + ldsB[j]));
    };
    // No inner barriers (R0-proven): 2-blocks/CU drift provides ds_read/MFMA overlap.
    auto compute = [&](const v4i* Asb, const v4i* Bsb) {
#pragma unroll
        for (int s = 0; s < 2; ++s) {
            v4i a[4], b[2];
#pragma unroll
            for (int mt = 0; mt < 4; ++mt) a[mt] = Asb[aSlot[mt][s]];
#pragma unroll
            for (int nt = 0; nt < 2; ++nt) b[nt] = Bsb[bSlot[nt][s]];
#pragma unroll
            for (int mt = 0; mt < 4; ++mt)
#pragma unroll
                for (int nt = 0; nt < 2; ++nt)
                    acc[mt][nt] = __builtin_amdgcn_mfma_i32_32x32x32_i8(
                        a[mt], b[nt], acc[mt][nt], 0, 0, 0);
        }
    };

    // ---- async double-buffered pipeline, counted vmcnt (never drains to 0
    // in the main loop: next tile's 6 loads stay in flight across barriers) ----
    stage(0, As0, Bs0);          // 6 vm-ops in flight
    stage(1, As1, Bs1);          // 12 in flight

#pragma unroll 1
    for (int kk = 0; kk < 31; ++kk) {
        const int k = 2 * kk;
        // even: consume buf0
        __builtin_amdgcn_s_waitcnt(WAIT_VM6);   // tile k landed; tile k+1 still flying
        __builtin_amdgcn_s_barrier();
        compute(As0, Bs0);
        __builtin_amdgcn_s_barrier();           // everyone done reading buf0
        stage(k + 2, As0, Bs0);
        // odd: consume buf1
        __builtin_amdgcn_s_waitcnt(WAIT_VM6);   // tile k+1 landed; tile k+2 flying
        __builtin_amdgcn_s_barrier();
        compute(As1, Bs1);
        __builtin_amdgcn_s_barrier();           // everyone done reading buf1
        stage(k + 3, As1, Bs1);
    }
    // peeled tail: tiles 62, 63
    __builtin_amdgcn_s_waitcnt(WAIT_VM6);
    __builtin_amdgcn_s_barrier();
    compute(As0, Bs0);
    __builtin_amdgcn_s_waitcnt(WAIT_VM0);
    __builtin_amdgcn_s_barrier();
    compute(As1, Bs1);

    // ---- epilogue: dequant + bias, requant to [0,255] ----
    // C/D 32x32: col = lane&31, row = (reg&3) + 8*(reg>>2) + 4*(lane>>5)
    const float scale  = xs_p[0] * ws_p[0];
    const float inv_os = 1.0f / os_p[0];
    const int   ozp    = ozp_p[0];
#pragma unroll
    for (int mt = 0; mt < 4; ++mt) {
        const int rbase = m0 + waveM * 128 + mt * 32 + 4 * h;
#pragma unroll
        for (int nt = 0; nt < 2; ++nt) {
            const int col = n0 + waveN * 64 + nt * 32 + l31;
            const float bv = bias[col];
#pragma unroll
            for (int r = 0; r < 16; ++r) {
                const int row = rbase + (r & 3) + 8 * (r >> 2);
                float y = (float)acc[mt][nt][r] * scale + bv;
                int q = (int)rintf(y * inv_os) + ozp;
                q = q < 0 ? 0 : (q > 255 ? 255 : q);
                out[(long)row * N_DIM + col] = q;
            }
        }
    }
}

extern "C" void kernel_launch(void* const* d_in, const int* in_sizes, int n_in,
                              void* d_out, int out_size, void* d_ws, size_t ws_size,
                              hipStream_t stream) {
    const int*   x_q  = (const int*)d_in[0];
    const int*   w_q  = (const int*)d_in[1];
    const float* bias = (const float*)d_in[2];
    const float* xs   = (const float*)d_in[3];
    const float* wsc  = (const float*)d_in[4];
    const float* os   = (const float*)d_in[5];
    const int*   xzp  = (const int*)d_in[6];
    const int*   ozp  = (const int*)d_in[7];

    signed char* x8 = (signed char*)d_ws;                               // 16 MB
    signed char* w8 = (signed char*)d_ws + (size_t)M_DIM * K_DIM;       // 45 MB

    const int nx16 = M_DIM * K_DIM / 16;
    const int nw16 = N_DIM * K_DIM / 16;
    const int npack = nx16 + nw16;
    pack_both_kernel<<<(npack + 255) / 256, 256, 0, stream>>>(
        x_q, w_q, (unsigned int*)x8, (unsigned int*)w8, xzp, nx16, nw16);

    const int nblocks = (M_DIM / BM) * (N_DIM / BN);   // 16 * 86 = 1376
    gemm_i8_kernel<<<nblocks, 256, 0, stream>>>(x8, w8, bias, xs, wsc, os, ozp, (int*)d_out);
}

// Round 5
// 533.674 us; speedup vs baseline: 1.0412x; 1.0235x over previous
//
#include <hip/hip_runtime.h>

#define M_DIM 4096
#define K_DIM 4096
#define N_DIM 11008
#define BM 256
#define BN 128
#define BK 64    // bytes of K per tile iteration (int8)
#define NTILES (K_DIM / BK)   // 64

typedef int v4i  __attribute__((ext_vector_type(4)));
typedef int v16i __attribute__((ext_vector_type(16)));

// s_waitcnt immediates (gfx90a+ encoding: vmcnt[3:0]+[15:14], exp[6:4], lgkm[13:8])
#define WAIT_VM6 0x3F76   // vmcnt<=6  (one stage() = 6 loads still in flight)
#define WAIT_VM0 0x3F70   // vmcnt<=0

__device__ __forceinline__ void load_lds16(const void* g, void* l) {
    __builtin_amdgcn_global_load_lds(
        (const __attribute__((address_space(1))) void*)g,
        (__attribute__((address_space(3))) void*)l,
        16, 0, 0);
}

__device__ __forceinline__ unsigned int pack4(int4 v, int zp) {
    return ((unsigned int)(v.x - zp) & 0xFF)
         | (((unsigned int)(v.y - zp) & 0xFF) << 8)
         | (((unsigned int)(v.z - zp) & 0xFF) << 16)
         | (((unsigned int)(v.w - zp) & 0xFF) << 24);
}

// Fused pack: one launch covers x (with zero-point) then w (zp=0).
__global__ void pack_both_kernel(const int* __restrict__ x, const int* __restrict__ w,
                                 unsigned int* __restrict__ x8, unsigned int* __restrict__ w8,
                                 const int* __restrict__ zp_p, int nx16, int nw16) {
    int i = blockIdx.x * blockDim.x + threadIdx.x;
    if (i < nx16) {
        const int zp = zp_p[0];
        const int4* p = (const int4*)x + i * 4;
        uint4 o;
        o.x = pack4(p[0], zp);
        o.y = pack4(p[1], zp);
        o.z = pack4(p[2], zp);
        o.w = pack4(p[3], zp);
        ((uint4*)x8)[i] = o;
    } else {
        int j = i - nx16;
        if (j >= nw16) return;
        const int4* p = (const int4*)w + j * 4;
        uint4 o;
        o.x = pack4(p[0], 0);
        o.y = pack4(p[1], 0);
        o.z = pack4(p[2], 0);
        o.w = pack4(p[3], 0);
        ((uint4*)w8)[j] = o;
    }
}

// Config rationale (R3/R4 post-mortems):
//  - 2 blocks/CU co-residency absorbs sync bubbles (R0 proven; single-block
//    R2/R3 exposed ~3500 cyc/tile of stalls).
//  - acc[4][2]=128 AGPR + ~100 VGPR <= 256/wave -> 2 waves/SIMD -> two
//    4-wave blocks/CU.
//  - Wave tile 128x64: 0.75 ds_reads/MFMA; BK=64 stage = 0.375 KB/MFMA ->
//    LDS 9.0 cyc/MFMA vs MFMA 9.14 cyc/MFMA (balanced pipes).
//
// LDS swizzle (R4 fix): 4 granules of 16B per 64B row; granule g of row r
// stored at POSITION g ^ ((r>>1)&3) in the row (slot = r*4 + pos).
// WHY (r>>1)&3 and not r&3: ds_read phases half-waves at a fixed granule
// index; position = 4*(r&1) + (g ^ f(r)). With f=(r&3) the (r&1) and f bits
// correlate -> only 4 of 8 positions per half-wave -> 16 banks -> 2x
// serialization (measured 5.07e7 conflicts, 3x R3). With f=((r>>1)&3) the
// pair (r&1, f) enumerates all 8 positions over 8 rows -> all 32 banks.
// The SAME involution is applied to the pre-swizzled GLOBAL source granule
// (gg) so global_load_lds's linear dest receives swizzled data (rule:
// swizzle both sides or neither).
__global__ __launch_bounds__(256, 2) void gemm_i8_kernel(
    const signed char* __restrict__ A8,   // [M][K] int8 (x - zp)
    const signed char* __restrict__ B8,   // [N][K] int8 (w)
    const float* __restrict__ bias,
    const float* __restrict__ xs_p, const float* __restrict__ ws_p,
    const float* __restrict__ os_p, const int* __restrict__ ozp_p,
    int* __restrict__ out) {
    __shared__ v4i As0[BM * BK / 16];   // 16 KB
    __shared__ v4i Bs0[BN * BK / 16];   // 8 KB
    __shared__ v4i As1[BM * BK / 16];
    __shared__ v4i Bs1[BN * BK / 16];   // 48 KB total -> 2 blocks/CU (96 of 160 KB)

    const int tid  = threadIdx.x;
    const int lane = tid & 63;
    const int wave = tid >> 6;

    // ---- XCD-aware block swizzle: 1376 blocks = 8 XCD x (2 m-tiles x 86 n-tiles)
    const int bid   = blockIdx.x;
    const int xcd   = bid & 7;
    const int local = bid >> 3;                    // [0, 172)
    const int m_blk = xcd * 2 + (local >= 86 ? 1 : 0);
    const int n_blk = (local >= 86) ? (local - 86) : local;
    const int m0 = m_blk * BM;
    const int n0 = n_blk * BN;

    // ---- staging addresses: per thread 4 A granules + 2 B granules per tile ----
    long offA[4], offB[2];
    int  ldsA[4], ldsB[2];
#pragma unroll
    for (int j = 0; j < 4; ++j) {
        const int s   = tid + 256 * j;             // A slot [0,1024)
        const int row = s >> 2;
        const int gg  = (s & 3) ^ ((row >> 1) & 3); // pre-swizzled source granule
        offA[j] = (long)(m0 + row) * K_DIM + gg * 16;
        ldsA[j] = s;
    }
#pragma unroll
    for (int j = 0; j < 2; ++j) {
        const int s   = tid + 256 * j;             // B slot [0,512)
        const int row = s >> 2;
        const int gg  = (s & 3) ^ ((row >> 1) & 3);
        offB[j] = (long)(n0 + row) * K_DIM + gg * 16;
        ldsB[j] = s;
    }

    // ---- fragment slots for mfma_i32_32x32x32_i8 ----
    // A/B operand: m(or n) = lane&31, k bytes [(lane>>5)*16, +16)
    const int waveM = wave >> 1, waveN = wave & 1;
    const int l31 = lane & 31, h = lane >> 5;
    int aSlot[4][2], bSlot[2][2];
#pragma unroll
    for (int mt = 0; mt < 4; ++mt) {
        const int rA = waveM * 128 + mt * 32 + l31;
#pragma unroll
        for (int s = 0; s < 2; ++s) {
            const int g = 2 * s + h;
            aSlot[mt][s] = rA * 4 + (g ^ ((rA >> 1) & 3));
        }
    }
#pragma unroll
    for (int nt = 0; nt < 2; ++nt) {
        const int rB = waveN * 64 + nt * 32 + l31;
#pragma unroll
        for (int s = 0; s < 2; ++s) {
            const int g = 2 * s + h;
            bSlot[nt][s] = rB * 4 + (g ^ ((rB >> 1) & 3));
        }
    }

    v16i acc[4][2];
#pragma unroll
    for (int mt = 0; mt < 4; ++mt)
#pragma unroll
        for (int nt = 0; nt < 2; ++nt)
#pragma unroll
            for (int r = 0; r < 16; ++r) acc[mt][nt][r] = 0;

    // ---- helpers ----
    auto stage = [&](int tile, v4i* Asb, v4i* Bsb) {
        const long koff = (long)tile * BK;
#pragma unroll
        for (int j = 0; j < 4; ++j) load_lds16(A8 + offA[j] + koff, (char*)(Asb + ldsA[j]));
#pragma unroll
        for (int j = 0; j < 2; ++j) load_lds16(B8 + offB[j] + koff, (char*)(Bsb + ldsB[j]));
    };
    // No inner barriers (R0-proven): 2-blocks/CU drift provides ds_read/MFMA overlap.
    auto compute = [&](const v4i* Asb, const v4i* Bsb) {
#pragma unroll
        for (int s = 0; s < 2; ++s) {
            v4i a[4], b[2];
#pragma unroll
            for (int mt = 0; mt < 4; ++mt) a[mt] = Asb[aSlot[mt][s]];
#pragma unroll
            for (int nt = 0; nt < 2; ++nt) b[nt] = Bsb[bSlot[nt][s]];
#pragma unroll
            for (int mt = 0; mt < 4; ++mt)
#pragma unroll
                for (int nt = 0; nt < 2; ++nt)
                    acc[mt][nt] = __builtin_amdgcn_mfma_i32_32x32x32_i8(
                        a[mt], b[nt], acc[mt][nt], 0, 0, 0);
        }
    };

    // ---- async double-buffered pipeline, counted vmcnt (never drains to 0
    // in the main loop: next tile's 6 loads stay in flight across barriers) ----
    stage(0, As0, Bs0);          // 6 vm-ops in flight
    stage(1, As1, Bs1);          // 12 in flight

#pragma unroll 1
    for (int kk = 0; kk < 31; ++kk) {
        const int k = 2 * kk;
        // even: consume buf0
        __builtin_amdgcn_s_waitcnt(WAIT_VM6);   // tile k landed; tile k+1 still flying
        __builtin_amdgcn_s_barrier();
        compute(As0, Bs0);
        __builtin_amdgcn_s_barrier();           // everyone done reading buf0
        stage(k + 2, As0, Bs0);
        // odd: consume buf1
        __builtin_amdgcn_s_waitcnt(WAIT_VM6);   // tile k+1 landed; tile k+2 flying
        __builtin_amdgcn_s_barrier();
        compute(As1, Bs1);
        __builtin_amdgcn_s_barrier();           // everyone done reading buf1
        stage(k + 3, As1, Bs1);
    }
    // peeled tail: tiles 62, 63
    __builtin_amdgcn_s_waitcnt(WAIT_VM6);
    __builtin_amdgcn_s_barrier();
    compute(As0, Bs0);
    __builtin_amdgcn_s_waitcnt(WAIT_VM0);
    __builtin_amdgcn_s_barrier();
    compute(As1, Bs1);

    // ---- epilogue: dequant + bias, requant to [0,255] ----
    // C/D 32x32: col = lane&31, row = (reg&3) + 8*(reg>>2) + 4*(lane>>5)
    const float scale  = xs_p[0] * ws_p[0];
    const float inv_os = 1.0f / os_p[0];
    const int   ozp    = ozp_p[0];
#pragma unroll
    for (int mt = 0; mt < 4; ++mt) {
        const int rbase = m0 + waveM * 128 + mt * 32 + 4 * h;
#pragma unroll
        for (int nt = 0; nt < 2; ++nt) {
            const int col = n0 + waveN * 64 + nt * 32 + l31;
            const float bv = bias[col];
#pragma unroll
            for (int r = 0; r < 16; ++r) {
                const int row = rbase + (r & 3) + 8 * (r >> 2);
                float y = (float)acc[mt][nt][r] * scale + bv;
                int q = (int)rintf(y * inv_os) + ozp;
                q = q < 0 ? 0 : (q > 255 ? 255 : q);
                out[(long)row * N_DIM + col] = q;
            }
        }
    }
}

extern "C" void kernel_launch(void* const* d_in, const int* in_sizes, int n_in,
                              void* d_out, int out_size, void* d_ws, size_t ws_size,
                              hipStream_t stream) {
    const int*   x_q  = (const int*)d_in[0];
    const int*   w_q  = (const int*)d_in[1];
    const float* bias = (const float*)d_in[2];
    const float* xs   = (const float*)d_in[3];
    const float* wsc  = (const float*)d_in[4];
    const float* os   = (const float*)d_in[5];
    const int*   xzp  = (const int*)d_in[6];
    const int*   ozp  = (const int*)d_in[7];

    signed char* x8 = (signed char*)d_ws;                               // 16 MB
    signed char* w8 = (signed char*)d_ws + (size_t)M_DIM * K_DIM;       // 45 MB

    const int nx16 = M_DIM * K_DIM / 16;
    const int nw16 = N_DIM * K_DIM / 16;
    const int npack = nx16 + nw16;
    pack_both_kernel<<<(npack + 255) / 256, 256, 0, stream>>>(
        x_q, w_q, (unsigned int*)x8, (unsigned int*)w8, xzp, nx16, nw16);

    const int nblocks = (M_DIM / BM) * (N_DIM / BN);   // 16 * 86 = 1376
    gemm_i8_kernel<<<nblocks, 256, 0, stream>>>(x8, w8, bias, xs, wsc, os, ozp, (int*)d_out);
}